// Round 2
// baseline (414.462 us; speedup 1.0000x reference)
//
#include <hip/hip_runtime.h>
#include <hip/hip_bf16.h>
#include <cstdint>
#include <cstddef>

#define N_TOK 8192
#define D_IN  1024
#define D_OUT 1024
#define N_EXP 8
#define KTOT  (N_EXP * D_IN)   // 8192

typedef __attribute__((ext_vector_type(8))) short short8;
typedef __attribute__((ext_vector_type(8))) unsigned short ushort8;
typedef __attribute__((ext_vector_type(4))) float f32x4;

// RNE float->bf16 (inputs are finite; no NaN handling needed)
__device__ __forceinline__ unsigned short f2bf(float f) {
    union { float f; unsigned int u; } v; v.f = f;
    return (unsigned short)((v.u + 0x7FFFu + ((v.u >> 16) & 1u)) >> 16);
}

__device__ __forceinline__ void load_lds16(const void* g, void* l) {
    __builtin_amdgcn_global_load_lds(
        (const __attribute__((address_space(1))) void*)g,
        (__attribute__((address_space(3))) void*)l,
        16, 0, 0);
}

// ---------------------------------------------------------------------------
// Kernel 1P: fused gate softmax + pre-scaled A write.
// One block per token. A_s[n][e*1024+i] = bf16(g[n,e] * x[n,i]); g_t[e][n].
// ---------------------------------------------------------------------------
__global__ __launch_bounds__(256) void gate_scale_kernel(
    const float* __restrict__ x, const float* __restrict__ gW,
    const float* __restrict__ gb, unsigned short* __restrict__ As,
    float* __restrict__ g_t) {
    const int n = blockIdx.x;
    const int t = threadIdx.x;

    const float4 xv = *(const float4*)(x + (size_t)n * D_IN + 4 * t);

    // partial gate dots: this thread covers i = 4t..4t+3
    float acc[8];
#pragma unroll
    for (int e = 0; e < 8; ++e) acc[e] = 0.f;
    const float xs[4] = {xv.x, xv.y, xv.z, xv.w};
#pragma unroll
    for (int j = 0; j < 4; ++j) {
        const float* wr = gW + (size_t)(4 * t + j) * N_EXP;
        const float4 w0 = *(const float4*)wr;
        const float4 w1 = *(const float4*)(wr + 4);
        acc[0] += xs[j] * w0.x; acc[1] += xs[j] * w0.y;
        acc[2] += xs[j] * w0.z; acc[3] += xs[j] * w0.w;
        acc[4] += xs[j] * w1.x; acc[5] += xs[j] * w1.y;
        acc[6] += xs[j] * w1.z; acc[7] += xs[j] * w1.w;
    }
#pragma unroll
    for (int off = 32; off > 0; off >>= 1) {
#pragma unroll
        for (int e = 0; e < 8; ++e) acc[e] += __shfl_down(acc[e], off);
    }
    __shared__ float red[4][8];
    __shared__ float gsh[8];
    if ((t & 63) == 0) {
#pragma unroll
        for (int e = 0; e < 8; ++e) red[t >> 6][e] = acc[e];
    }
    __syncthreads();
    if (t == 0) {
        float lg[8], mx = -1e30f;
#pragma unroll
        for (int e = 0; e < 8; ++e) {
            lg[e] = red[0][e] + red[1][e] + red[2][e] + red[3][e] + gb[e];
            mx = fmaxf(mx, lg[e]);
        }
        float s = 0.f;
#pragma unroll
        for (int e = 0; e < 8; ++e) { lg[e] = expf(lg[e] - mx); s += lg[e]; }
        const float inv = 1.f / s;
#pragma unroll
        for (int e = 0; e < 8; ++e) {
            const float g = lg[e] * inv;
            g_t[(size_t)e * N_TOK + n] = g;
            gsh[e] = g;
        }
    }
    __syncthreads();
#pragma unroll
    for (int e = 0; e < 8; ++e) {
        const float g = gsh[e];
        ushort4 u;
        u.x = f2bf(g * xv.x); u.y = f2bf(g * xv.y);
        u.z = f2bf(g * xv.z); u.w = f2bf(g * xv.w);
        *(ushort4*)(As + (size_t)n * KTOT + e * D_IN + 4 * t) = u;
    }
}

// ---------------------------------------------------------------------------
// Kernel 1F (fallback): fused gate softmax + x fp32->bf16 convert.
// ---------------------------------------------------------------------------
__global__ __launch_bounds__(256) void gate_xconv_kernel(
    const float* __restrict__ x, const float* __restrict__ gW,
    const float* __restrict__ gb, unsigned short* __restrict__ xb,
    float* __restrict__ g_t) {
    const int n = blockIdx.x;
    const int t = threadIdx.x;

    const float4 xv = *(const float4*)(x + (size_t)n * D_IN + 4 * t);
    ushort4 u;
    u.x = f2bf(xv.x); u.y = f2bf(xv.y); u.z = f2bf(xv.z); u.w = f2bf(xv.w);
    *(ushort4*)(xb + (size_t)n * D_IN + 4 * t) = u;

    float acc[8];
#pragma unroll
    for (int e = 0; e < 8; ++e) acc[e] = 0.f;
    const float xs[4] = {xv.x, xv.y, xv.z, xv.w};
#pragma unroll
    for (int j = 0; j < 4; ++j) {
        const float* wr = gW + (size_t)(4 * t + j) * N_EXP;
        const float4 w0 = *(const float4*)wr;
        const float4 w1 = *(const float4*)(wr + 4);
        acc[0] += xs[j] * w0.x; acc[1] += xs[j] * w0.y;
        acc[2] += xs[j] * w0.z; acc[3] += xs[j] * w0.w;
        acc[4] += xs[j] * w1.x; acc[5] += xs[j] * w1.y;
        acc[6] += xs[j] * w1.z; acc[7] += xs[j] * w1.w;
    }
#pragma unroll
    for (int off = 32; off > 0; off >>= 1) {
#pragma unroll
        for (int e = 0; e < 8; ++e) acc[e] += __shfl_down(acc[e], off);
    }
    __shared__ float red[4][8];
    if ((t & 63) == 0) {
#pragma unroll
        for (int e = 0; e < 8; ++e) red[t >> 6][e] = acc[e];
    }
    __syncthreads();
    if (t == 0) {
        float lg[8], mx = -1e30f;
#pragma unroll
        for (int e = 0; e < 8; ++e) {
            lg[e] = red[0][e] + red[1][e] + red[2][e] + red[3][e] + gb[e];
            mx = fmaxf(mx, lg[e]);
        }
        float s = 0.f;
#pragma unroll
        for (int e = 0; e < 8; ++e) { lg[e] = expf(lg[e] - mx); s += lg[e]; }
        const float inv = 1.f / s;
#pragma unroll
        for (int e = 0; e < 8; ++e) g_t[(size_t)e * N_TOK + n] = lg[e] * inv;
    }
}

// ---------------------------------------------------------------------------
// Kernel 2: W [e][i][o] fp32 -> W_t [o][e*1024+i] bf16.
// Read stage: wave = 4 rows x 256B contiguous (full coalescing).
// LDS pad 65 -> 2-way bank aliasing on both stages (free per m136).
// ---------------------------------------------------------------------------
__global__ __launch_bounds__(256) void wconv_kernel(
    const float* __restrict__ W, unsigned short* __restrict__ Wt) {
    __shared__ float tile[64][65];
    const int e  = blockIdx.z;
    const int i0 = blockIdx.y * 64;
    const int o0 = blockIdx.x * 64;
    const int t  = threadIdx.x;

    // read: row = (t>>4) + 16j (i-dim), col = (t&15)*4 (o-dim)
    const int rr = t >> 4;
    const int rc = (t & 15) * 4;
#pragma unroll
    for (int j = 0; j < 4; ++j) {
        const float4 v = *(const float4*)(
            W + ((size_t)e * D_IN + (i0 + rr + 16 * j)) * D_OUT + o0 + rc);
        tile[rr + 16 * j][rc + 0] = v.x;
        tile[rr + 16 * j][rc + 1] = v.y;
        tile[rr + 16 * j][rc + 2] = v.z;
        tile[rr + 16 * j][rc + 3] = v.w;
    }
    __syncthreads();
    // write: o-row = t>>2, i-chunk = (t&3)*16
    const int ow = t >> 2;
    const int c  = (t & 3) * 16;
    ushort8 v0, v1;
#pragma unroll
    for (int j = 0; j < 8; ++j) v0[j] = f2bf(tile[c + j][ow]);
#pragma unroll
    for (int j = 0; j < 8; ++j) v1[j] = f2bf(tile[c + 8 + j][ow]);
    unsigned short* dst = Wt + (size_t)(o0 + ow) * KTOT + e * D_IN + i0 + c;
    *(ushort8*)dst = v0;
    *(ushort8*)(dst + 8) = v1;
}

// ---------------------------------------------------------------------------
// Kernel 3P: single-accumulator GEMM (m97 structure), K = 8192 over A_s.
// out[n][o] = sum_k A_s[n][k]*Wt[o][k]  +  sum_e g[n,e]*b[e,o] (epilogue).
// ---------------------------------------------------------------------------
__global__ __launch_bounds__(256, 3) void gemm_single_kernel(
    const unsigned short* __restrict__ As,   // [N_TOK][KTOT] bf16 (pre-scaled)
    const unsigned short* __restrict__ Wt,   // [D_OUT][KTOT] bf16
    const float* __restrict__ bias,          // [N_EXP][D_OUT]
    const float* __restrict__ g_t,           // [N_EXP][N_TOK]
    float* __restrict__ out) {               // [N_TOK][D_OUT]
    __shared__ __align__(16) unsigned short Abuf[128 * 32];
    __shared__ __align__(16) unsigned short Bbuf[128 * 32];
    __shared__ __align__(16) float g_s[N_EXP][128];
    __shared__ __align__(16) float b_s[N_EXP][128];

    const int t    = threadIdx.x;
    const int lane = t & 63;
    const int ln15 = lane & 15;
    const int quad = lane >> 4;
    const int wave = t >> 6;
    const int wm0  = (wave >> 1) * 64;
    const int wn0  = (wave & 1) * 64;
    const int bm0  = blockIdx.y * 128;
    const int bn0  = blockIdx.x * 128;

    for (int j = t; j < N_EXP * 128; j += 256) {
        const int e = j >> 7, r = j & 127;
        g_s[e][r] = g_t[(size_t)e * N_TOK + bm0 + r];
        b_s[e][r] = bias[(size_t)e * D_OUT + bn0 + r];
    }

    f32x4 acc[4][4];
#pragma unroll
    for (int mi = 0; mi < 4; ++mi)
#pragma unroll
        for (int ni = 0; ni < 4; ++ni)
            acc[mi][ni] = (f32x4){0.f, 0.f, 0.f, 0.f};

    unsigned short* aLds0 = &Abuf[wave * 512];
    unsigned short* aLds1 = &Abuf[2048 + wave * 512];
    unsigned short* bLds0 = &Bbuf[wave * 512];
    unsigned short* bLds1 = &Bbuf[2048 + wave * 512];

    const unsigned short* ga =
        As + (size_t)(bm0 + (t >> 2)) * KTOT + (t & 3) * 8;
    const unsigned short* gb =
        Wt + (size_t)(bn0 + (t >> 2)) * KTOT + (t & 3) * 8;

    __syncthreads();  // g_s/b_s ready (also first-iter tile safety)

    for (int kk = 0; kk < 256; ++kk) {
        __syncthreads();
        load_lds16(ga + kk * 32,              aLds0);
        load_lds16(ga + 64 * KTOT + kk * 32,  aLds1);
        load_lds16(gb + kk * 32,              bLds0);
        load_lds16(gb + 64 * KTOT + kk * 32,  bLds1);
        __syncthreads();

        short8 af[4], bv[4];
#pragma unroll
        for (int mi = 0; mi < 4; ++mi)
            af[mi] = *(const short8*)&Abuf[(wm0 + mi * 16 + ln15) * 32 + quad * 8];
#pragma unroll
        for (int ni = 0; ni < 4; ++ni)
            bv[ni] = *(const short8*)&Bbuf[(wn0 + ni * 16 + ln15) * 32 + quad * 8];
#pragma unroll
        for (int mi = 0; mi < 4; ++mi)
#pragma unroll
            for (int ni = 0; ni < 4; ++ni)
                acc[mi][ni] = __builtin_amdgcn_mfma_f32_16x16x32_bf16(
                    af[mi], bv[ni], acc[mi][ni], 0, 0, 0);
    }

    // epilogue: add sum_e g[row,e]*b[e,col]
#pragma unroll
    for (int e = 0; e < N_EXP; ++e) {
        f32x4 gv[4];
        float bv[4];
#pragma unroll
        for (int mi = 0; mi < 4; ++mi)
            gv[mi] = *(const f32x4*)&g_s[e][wm0 + mi * 16 + quad * 4];
#pragma unroll
        for (int ni = 0; ni < 4; ++ni) bv[ni] = b_s[e][wn0 + ni * 16 + ln15];
#pragma unroll
        for (int mi = 0; mi < 4; ++mi)
#pragma unroll
            for (int ni = 0; ni < 4; ++ni)
#pragma unroll
                for (int r = 0; r < 4; ++r)
                    acc[mi][ni][r] += gv[mi][r] * bv[ni];
    }

#pragma unroll
    for (int mi = 0; mi < 4; ++mi) {
#pragma unroll
        for (int ni = 0; ni < 4; ++ni) {
            const int col  = bn0 + wn0 + ni * 16 + ln15;
            const int row0 = bm0 + wm0 + mi * 16 + quad * 4;
#pragma unroll
            for (int r = 0; r < 4; ++r)
                out[(size_t)(row0 + r) * D_OUT + col] = acc[mi][ni][r];
        }
    }
}

// ---------------------------------------------------------------------------
// Kernel 3F (fallback, proven R1): dual-accumulator, expert-boundary rescale.
// ---------------------------------------------------------------------------
__global__ __launch_bounds__(256, 2) void moe_gemm_kernel(
    const unsigned short* __restrict__ xb,
    const unsigned short* __restrict__ Wt,
    const float* __restrict__ bias,
    const float* __restrict__ g_t,
    float* __restrict__ out) {
    __shared__ __align__(16) unsigned short Abuf[128 * 32];
    __shared__ __align__(16) unsigned short Bbuf[128 * 32];
    __shared__ __align__(16) float g_s[N_EXP][128];
    __shared__ __align__(16) float b_s[N_EXP][128];

    const int t    = threadIdx.x;
    const int lane = t & 63;
    const int ln15 = lane & 15;
    const int quad = lane >> 4;
    const int wave = t >> 6;
    const int wm0  = (wave >> 1) * 64;
    const int wn0  = (wave & 1) * 64;
    const int bm0  = blockIdx.y * 128;
    const int bn0  = blockIdx.x * 128;

    for (int j = t; j < N_EXP * 128; j += 256) {
        const int e = j >> 7, r = j & 127;
        g_s[e][r] = g_t[(size_t)e * N_TOK + bm0 + r];
        b_s[e][r] = bias[(size_t)e * D_OUT + bn0 + r];
    }

    f32x4 accF[4][4];
#pragma unroll
    for (int mi = 0; mi < 4; ++mi)
#pragma unroll
        for (int ni = 0; ni < 4; ++ni)
            accF[mi][ni] = (f32x4){0.f, 0.f, 0.f, 0.f};

    unsigned short* aLds0 = &Abuf[wave * 512];
    unsigned short* aLds1 = &Abuf[2048 + wave * 512];
    unsigned short* bLds0 = &Bbuf[wave * 512];
    unsigned short* bLds1 = &Bbuf[2048 + wave * 512];

    const unsigned short* gaBase =
        xb + (size_t)(bm0 + (t >> 2)) * D_IN + (t & 3) * 8;
    const unsigned short* gbBase =
        Wt + (size_t)(bn0 + (t >> 2)) * KTOT + (t & 3) * 8;

    __syncthreads();

    for (int e = 0; e < N_EXP; ++e) {
        float bval[4];
#pragma unroll
        for (int ni = 0; ni < 4; ++ni) bval[ni] = b_s[e][wn0 + ni * 16 + ln15];
        f32x4 acc[4][4];
#pragma unroll
        for (int mi = 0; mi < 4; ++mi)
#pragma unroll
            for (int ni = 0; ni < 4; ++ni)
                acc[mi][ni] = (f32x4){bval[ni], bval[ni], bval[ni], bval[ni]};

        const unsigned short* ga = gaBase;
        const unsigned short* gb = gbBase + e * D_IN;

        for (int kk = 0; kk < 32; ++kk) {
            __syncthreads();
            load_lds16(ga + kk * 32,              aLds0);
            load_lds16(ga + 64 * D_IN + kk * 32,  aLds1);
            load_lds16(gb + kk * 32,              bLds0);
            load_lds16(gb + 64 * KTOT + kk * 32,  bLds1);
            __syncthreads();

            short8 af[4], bv[4];
#pragma unroll
            for (int mi = 0; mi < 4; ++mi)
                af[mi] = *(const short8*)&Abuf[(wm0 + mi * 16 + ln15) * 32 + quad * 8];
#pragma unroll
            for (int ni = 0; ni < 4; ++ni)
                bv[ni] = *(const short8*)&Bbuf[(wn0 + ni * 16 + ln15) * 32 + quad * 8];
#pragma unroll
            for (int mi = 0; mi < 4; ++mi)
#pragma unroll
                for (int ni = 0; ni < 4; ++ni)
                    acc[mi][ni] = __builtin_amdgcn_mfma_f32_16x16x32_bf16(
                        af[mi], bv[ni], acc[mi][ni], 0, 0, 0);
        }

#pragma unroll
        for (int mi = 0; mi < 4; ++mi) {
            const f32x4 gv = *(const f32x4*)&g_s[e][wm0 + mi * 16 + quad * 4];
#pragma unroll
            for (int ni = 0; ni < 4; ++ni) {
#pragma unroll
                for (int r = 0; r < 4; ++r)
                    accF[mi][ni][r] += gv[r] * acc[mi][ni][r];
            }
        }
    }

#pragma unroll
    for (int mi = 0; mi < 4; ++mi) {
#pragma unroll
        for (int ni = 0; ni < 4; ++ni) {
            const int col  = bn0 + wn0 + ni * 16 + ln15;
            const int row0 = bm0 + wm0 + mi * 16 + quad * 4;
#pragma unroll
            for (int r = 0; r < 4; ++r)
                out[(size_t)(row0 + r) * D_OUT + col] = accF[mi][ni][r];
        }
    }
}

// ---------------------------------------------------------------------------
extern "C" void kernel_launch(void* const* d_in, const int* in_sizes, int n_in,
                              void* d_out, int out_size, void* d_ws, size_t ws_size,
                              hipStream_t stream) {
    const float* x  = (const float*)d_in[0];
    const float* W  = (const float*)d_in[1];
    const float* b  = (const float*)d_in[2];
    const float* gW = (const float*)d_in[3];
    const float* gb = (const float*)d_in[4];
    float* out = (float*)d_out;

    const size_t needP = (size_t)N_TOK * KTOT * 2      // A_s  (128 MB)
                       + (size_t)D_OUT * KTOT * 2      // Wt   (16 MB)
                       + (size_t)N_EXP * N_TOK * 4;    // g_t  (256 KB)

    if (ws_size >= needP) {
        // Path P: pre-scaled A, single-accumulator m97-structure GEMM.
        unsigned short* As  = (unsigned short*)d_ws;
        unsigned short* Wt  = As + (size_t)N_TOK * KTOT;
        float*          g_t = (float*)(Wt + (size_t)D_OUT * KTOT);

        gate_scale_kernel<<<N_TOK, 256, 0, stream>>>(x, gW, gb, As, g_t);
        wconv_kernel<<<dim3(16, 16, 8), 256, 0, stream>>>(W, Wt);
        gemm_single_kernel<<<dim3(D_OUT / 128, N_TOK / 128), 256, 0, stream>>>(
            As, Wt, b, g_t, out);
    } else {
        // Path F: proven R1 structure.
        unsigned short* xb  = (unsigned short*)d_ws;
        unsigned short* Wt  = xb + (size_t)N_TOK * D_IN;
        float*          g_t = (float*)(Wt + (size_t)D_OUT * KTOT);

        gate_xconv_kernel<<<N_TOK, 256, 0, stream>>>(x, gW, gb, xb, g_t);
        wconv_kernel<<<dim3(16, 16, 8), 256, 0, stream>>>(W, Wt);
        moe_gemm_kernel<<<dim3(D_OUT / 128, N_TOK / 128), 256, 0, stream>>>(
            xb, Wt, b, g_t, out);
    }
}

// Round 3
// 369.810 us; speedup vs baseline: 1.1207x; 1.1207x over previous
//
#include <hip/hip_runtime.h>
#include <hip/hip_bf16.h>
#include <cstdint>
#include <cstddef>

#define N_TOK 8192
#define D_IN  1024
#define D_OUT 1024
#define N_EXP 8
#define KTOT  (N_EXP * D_IN)

typedef __attribute__((ext_vector_type(8))) short short8;
typedef __attribute__((ext_vector_type(8))) unsigned short ushort8;
typedef __attribute__((ext_vector_type(4))) float f32x4;

__device__ __forceinline__ unsigned short f2bf(float f) {
    union { float f; unsigned int u; } v; v.f = f;
    return (unsigned short)((v.u + 0x7FFFu + ((v.u >> 16) & 1u)) >> 16);
}

__device__ __forceinline__ void load_lds16(const void* g, void* l) {
    __builtin_amdgcn_global_load_lds(
        (const __attribute__((address_space(1))) void*)g,
        (__attribute__((address_space(3))) void*)l,
        16, 0, 0);
}

// ---------------------------------------------------------------------------
// Fused prep: blocks [0,2048) = W transpose+convert; [2048,2560) = gate+xconv.
// ---------------------------------------------------------------------------
__global__ __launch_bounds__(256) void prep_kernel(
    const float* __restrict__ x, const float* __restrict__ gW,
    const float* __restrict__ gb, const float* __restrict__ W,
    unsigned short* __restrict__ xb, unsigned short* __restrict__ Wt,
    float* __restrict__ g_t) {
    const int b = blockIdx.x;
    const int t = threadIdx.x;

    if (b < 2048) {
        // ---- wconv: W[e][i][o] fp32 -> Wt[o][e*1024+i] bf16 ----
        __shared__ float tile[64][65];
        const int e  = b >> 8;
        const int i0 = ((b >> 4) & 15) * 64;
        const int o0 = (b & 15) * 64;

        const int rr = t >> 4;          // 0..15
        const int rc = (t & 15) * 4;    // 0..60
#pragma unroll
        for (int j = 0; j < 4; ++j) {
            const float4 v = *(const float4*)(
                W + ((size_t)e * D_IN + (i0 + rr + 16 * j)) * D_OUT + o0 + rc);
            tile[rr + 16 * j][rc + 0] = v.x;
            tile[rr + 16 * j][rc + 1] = v.y;
            tile[rr + 16 * j][rc + 2] = v.z;
            tile[rr + 16 * j][rc + 3] = v.w;
        }
        __syncthreads();
        const int ow = t >> 2;          // 0..63 (o-row)
        const int c  = (t & 3) * 16;    // i-chunk
        ushort8 v0, v1;
#pragma unroll
        for (int j = 0; j < 8; ++j) v0[j] = f2bf(tile[c + j][ow]);
#pragma unroll
        for (int j = 0; j < 8; ++j) v1[j] = f2bf(tile[c + 8 + j][ow]);
        unsigned short* dst = Wt + (size_t)(o0 + ow) * KTOT + e * D_IN + i0 + c;
        *(ushort8*)dst = v0;
        *(ushort8*)(dst + 8) = v1;
    } else {
        // ---- gate + x->bf16: 16 tokens per block, 16 lanes per token ----
        const int n0   = (b - 2048) * 16;
        const int tok  = t >> 4;        // 0..15
        const int l16  = t & 15;
        const int n    = n0 + tok;

        float acc[8];
#pragma unroll
        for (int e = 0; e < 8; ++e) acc[e] = 0.f;

#pragma unroll 4
        for (int jj = 0; jj < 16; ++jj) {
            const int i = 64 * jj + 4 * l16;
            const float4 xv = *(const float4*)(x + (size_t)n * D_IN + i);
            ushort4 u;
            u.x = f2bf(xv.x); u.y = f2bf(xv.y);
            u.z = f2bf(xv.z); u.w = f2bf(xv.w);
            *(ushort4*)(xb + (size_t)n * D_IN + i) = u;
            const float xs[4] = {xv.x, xv.y, xv.z, xv.w};
#pragma unroll
            for (int j = 0; j < 4; ++j) {
                const float* wr = gW + (size_t)(i + j) * N_EXP;
                const float4 w0 = *(const float4*)wr;
                const float4 w1 = *(const float4*)(wr + 4);
                acc[0] += xs[j] * w0.x; acc[1] += xs[j] * w0.y;
                acc[2] += xs[j] * w0.z; acc[3] += xs[j] * w0.w;
                acc[4] += xs[j] * w1.x; acc[5] += xs[j] * w1.y;
                acc[6] += xs[j] * w1.z; acc[7] += xs[j] * w1.w;
            }
        }
        // reduce over the 16 lanes of this token
#pragma unroll
        for (int d = 8; d > 0; d >>= 1) {
#pragma unroll
            for (int e = 0; e < 8; ++e) acc[e] += __shfl_down(acc[e], d, 16);
        }
        if (l16 == 0) {
            float lg[8], mx = -1e30f;
#pragma unroll
            for (int e = 0; e < 8; ++e) {
                lg[e] = acc[e] + gb[e];
                mx = fmaxf(mx, lg[e]);
            }
            float s = 0.f;
#pragma unroll
            for (int e = 0; e < 8; ++e) { lg[e] = expf(lg[e] - mx); s += lg[e]; }
            const float inv = 1.f / s;
#pragma unroll
            for (int e = 0; e < 8; ++e)
                g_t[(size_t)e * N_TOK + n] = lg[e] * inv;
        }
    }
}

// ---------------------------------------------------------------------------
// GEMM: tile 128(M)x64(N), BK=32, single accumulator + telescoping gate
// rescale at expert boundaries. Grid (16,64)=1024 blocks, 3 blocks/CU.
// out[n][o] = d7*acc (= sum_e g_e * x W_e) + sum_e g_e * b[e][o].
// ---------------------------------------------------------------------------
__global__ __launch_bounds__(256, 3) void moe_gemm2_kernel(
    const unsigned short* __restrict__ xb,   // [N_TOK][D_IN] bf16
    const unsigned short* __restrict__ Wt,   // [D_OUT][KTOT] bf16
    const float* __restrict__ bias,          // [N_EXP][D_OUT]
    const float* __restrict__ g_t,           // [N_EXP][N_TOK]
    float* __restrict__ out) {               // [N_TOK][D_OUT]
    __shared__ __align__(16) unsigned short Abuf[128 * 32];  // 8 KB
    __shared__ __align__(16) unsigned short Bbuf[64 * 32];   // 4 KB
    __shared__ __align__(16) float g_s[N_EXP][128];          // true gates
    __shared__ __align__(16) float r_s[N_EXP][128];          // r_s[e>=1]=d[e-1]/d[e]; r_s[0]=d[7]
    __shared__ __align__(16) float b_s[N_EXP][64];

    const int t    = threadIdx.x;
    const int lane = t & 63;
    const int ln15 = lane & 15;
    const int quad = lane >> 4;
    const int wave = t >> 6;
    const int wm0  = (wave >> 1) * 64;   // 0 / 64
    const int wn0  = (wave & 1) * 32;    // 0 / 32
    const int bm0  = blockIdx.y * 128;
    const int bn0  = blockIdx.x * 64;

    for (int j = t; j < N_EXP * 128; j += 256) {
        const int e = j >> 7, r = j & 127;
        g_s[e][r] = g_t[(size_t)e * N_TOK + bm0 + r];
    }
    for (int j = t; j < N_EXP * 64; j += 256) {
        const int e = j >> 6, c = j & 63;
        b_s[e][c] = bias[(size_t)e * D_OUT + bn0 + c];
    }
    __syncthreads();
    if (t < 128) {
        float d[8];
#pragma unroll
        for (int e = 0; e < 8; ++e) d[e] = fmaxf(g_s[e][t], 1e-30f);
#pragma unroll
        for (int e = 1; e < 8; ++e) r_s[e][t] = d[e - 1] / d[e];
        r_s[0][t] = d[7];
    }

    f32x4 acc[4][2];
#pragma unroll
    for (int mi = 0; mi < 4; ++mi)
#pragma unroll
        for (int ni = 0; ni < 2; ++ni)
            acc[mi][ni] = (f32x4){0.f, 0.f, 0.f, 0.f};

    // wave-uniform LDS staging bases (HW adds lane*16B)
    unsigned short* aLds0 = &Abuf[wave * 512];           // rows 16w..16w+15
    unsigned short* aLds1 = &Abuf[2048 + wave * 512];    // rows 64+...
    unsigned short* bLds  = &Bbuf[wave * 512];

    const unsigned short* ga =
        xb + (size_t)(bm0 + (t >> 2)) * D_IN + (t & 3) * 8;
    const unsigned short* gbB =
        Wt + (size_t)(bn0 + (t >> 2)) * KTOT + (t & 3) * 8;

    __syncthreads();  // r_s ready

    for (int e = 0; e < N_EXP; ++e) {
        if (e) {  // acc *= d[e-1]/d[e] (per output row)
#pragma unroll
            for (int mi = 0; mi < 4; ++mi) {
                const f32x4 rv = *(const f32x4*)&r_s[e][wm0 + mi * 16 + quad * 4];
#pragma unroll
                for (int ni = 0; ni < 2; ++ni) {
#pragma unroll
                    for (int r = 0; r < 4; ++r) acc[mi][ni][r] *= rv[r];
                }
            }
        }
        const unsigned short* gbe = gbB + e * D_IN;

        for (int kk = 0; kk < 32; ++kk) {
            __syncthreads();
            load_lds16(ga + kk * 32,              aLds0);
            load_lds16(ga + 64 * D_IN + kk * 32,  aLds1);
            load_lds16(gbe + kk * 32,             bLds);
            __syncthreads();

            short8 af[4], bv[2];
#pragma unroll
            for (int mi = 0; mi < 4; ++mi)
                af[mi] = *(const short8*)&Abuf[(wm0 + mi * 16 + ln15) * 32 + quad * 8];
#pragma unroll
            for (int ni = 0; ni < 2; ++ni)
                bv[ni] = *(const short8*)&Bbuf[(wn0 + ni * 16 + ln15) * 32 + quad * 8];
#pragma unroll
            for (int mi = 0; mi < 4; ++mi)
#pragma unroll
                for (int ni = 0; ni < 2; ++ni)
                    acc[mi][ni] = __builtin_amdgcn_mfma_f32_16x16x32_bf16(
                        af[mi], bv[ni], acc[mi][ni], 0, 0, 0);
        }
    }

    // final scale by d[7], then add sum_e g_e * b[e][col]
#pragma unroll
    for (int mi = 0; mi < 4; ++mi) {
        const f32x4 fin = *(const f32x4*)&r_s[0][wm0 + mi * 16 + quad * 4];
#pragma unroll
        for (int ni = 0; ni < 2; ++ni)
#pragma unroll
            for (int r = 0; r < 4; ++r) acc[mi][ni][r] *= fin[r];
    }
#pragma unroll
    for (int e = 0; e < N_EXP; ++e) {
        f32x4 gv[4];
        float bv[2];
#pragma unroll
        for (int mi = 0; mi < 4; ++mi)
            gv[mi] = *(const f32x4*)&g_s[e][wm0 + mi * 16 + quad * 4];
#pragma unroll
        for (int ni = 0; ni < 2; ++ni) bv[ni] = b_s[e][wn0 + ni * 16 + ln15];
#pragma unroll
        for (int mi = 0; mi < 4; ++mi)
#pragma unroll
            for (int ni = 0; ni < 2; ++ni)
#pragma unroll
                for (int r = 0; r < 4; ++r)
                    acc[mi][ni][r] += gv[mi][r] * bv[ni];
    }

#pragma unroll
    for (int mi = 0; mi < 4; ++mi) {
#pragma unroll
        for (int ni = 0; ni < 2; ++ni) {
            const int col  = bn0 + wn0 + ni * 16 + ln15;
            const int row0 = bm0 + wm0 + mi * 16 + quad * 4;
#pragma unroll
            for (int r = 0; r < 4; ++r)
                out[(size_t)(row0 + r) * D_OUT + col] = acc[mi][ni][r];
        }
    }
}

// ---------------------------------------------------------------------------
extern "C" void kernel_launch(void* const* d_in, const int* in_sizes, int n_in,
                              void* d_out, int out_size, void* d_ws, size_t ws_size,
                              hipStream_t stream) {
    const float* x  = (const float*)d_in[0];
    const float* W  = (const float*)d_in[1];
    const float* b  = (const float*)d_in[2];
    const float* gW = (const float*)d_in[3];
    const float* gb = (const float*)d_in[4];
    float* out = (float*)d_out;

    unsigned short* xb  = (unsigned short*)d_ws;                 // 16 MB
    unsigned short* Wt  = xb + (size_t)N_TOK * D_IN;             // 16 MB
    float*          g_t = (float*)(Wt + (size_t)D_OUT * KTOT);   // 256 KB

    // 2048 wconv blocks + 512 gate blocks, one dispatch
    prep_kernel<<<2048 + 512, 256, 0, stream>>>(x, gW, gb, W, xb, Wt, g_t);
    moe_gemm2_kernel<<<dim3(D_OUT / 64, N_TOK / 128), 256, 0, stream>>>(
        xb, Wt, b, g_t, out);
}

// Round 4
// 325.570 us; speedup vs baseline: 1.2730x; 1.1359x over previous
//
#include <hip/hip_runtime.h>
#include <hip/hip_bf16.h>
#include <cstdint>
#include <cstddef>

#define N_TOK 8192
#define D_IN  1024
#define D_OUT 1024
#define N_EXP 8
#define HEXP  4                 // experts per K-split half
#define KTOT  (N_EXP * D_IN)

typedef __attribute__((ext_vector_type(8))) short short8;
typedef __attribute__((ext_vector_type(8))) unsigned short ushort8;
typedef __attribute__((ext_vector_type(4))) float f32x4;

__device__ __forceinline__ unsigned short f2bf(float f) {
    union { float f; unsigned int u; } v; v.f = f;
    return (unsigned short)((v.u + 0x7FFFu + ((v.u >> 16) & 1u)) >> 16);
}

__device__ __forceinline__ void load_lds16(const void* g, void* l) {
    __builtin_amdgcn_global_load_lds(
        (const __attribute__((address_space(1))) void*)g,
        (__attribute__((address_space(3))) void*)l,
        16, 0, 0);
}

// ---------------------------------------------------------------------------
// Fused prep, 5120 blocks:
//   [0,2048)    : W[e][i][o] fp32 -> Wt[o][e*1024+i] bf16 (64x64 transpose)
//   [2048,4096) : gate softmax + x->bf16, one WAVE per token (4 tokens/block)
//   [4096,5120) : zero out[] (32 KB/block) for the GEMM's atomicAdd combine
// ---------------------------------------------------------------------------
__global__ __launch_bounds__(256) void prep_kernel(
    const float* __restrict__ x, const float* __restrict__ gW,
    const float* __restrict__ gbias, const float* __restrict__ W,
    unsigned short* __restrict__ xb, unsigned short* __restrict__ Wt,
    float* __restrict__ g_t, float* __restrict__ outz) {
    const int b = blockIdx.x;
    const int t = threadIdx.x;

    if (b < 2048) {
        __shared__ float tile[64][65];
        const int e  = b >> 8;
        const int i0 = ((b >> 4) & 15) * 64;
        const int o0 = (b & 15) * 64;

        const int rr = t >> 4;
        const int rc = (t & 15) * 4;
#pragma unroll
        for (int j = 0; j < 4; ++j) {
            const float4 v = *(const float4*)(
                W + ((size_t)e * D_IN + (i0 + rr + 16 * j)) * D_OUT + o0 + rc);
            tile[rr + 16 * j][rc + 0] = v.x;
            tile[rr + 16 * j][rc + 1] = v.y;
            tile[rr + 16 * j][rc + 2] = v.z;
            tile[rr + 16 * j][rc + 3] = v.w;
        }
        __syncthreads();
        const int ow = t >> 2;
        const int c  = (t & 3) * 16;
        ushort8 v0, v1;
#pragma unroll
        for (int j = 0; j < 8; ++j) v0[j] = f2bf(tile[c + j][ow]);
#pragma unroll
        for (int j = 0; j < 8; ++j) v1[j] = f2bf(tile[c + 8 + j][ow]);
        unsigned short* dst = Wt + (size_t)(o0 + ow) * KTOT + e * D_IN + i0 + c;
        *(ushort8*)dst = v0;
        *(ushort8*)(dst + 8) = v1;
    } else if (b < 4096) {
        // one wave per token
        const int lane = t & 63;
        const int n    = (b - 2048) * 4 + (t >> 6);

        float acc[8];
#pragma unroll
        for (int e = 0; e < 8; ++e) acc[e] = 0.f;
#pragma unroll
        for (int jj = 0; jj < 4; ++jj) {
            const int i = 256 * jj + 4 * lane;
            const float4 xv = *(const float4*)(x + (size_t)n * D_IN + i);
            ushort4 u;
            u.x = f2bf(xv.x); u.y = f2bf(xv.y);
            u.z = f2bf(xv.z); u.w = f2bf(xv.w);
            *(ushort4*)(xb + (size_t)n * D_IN + i) = u;
            const float xs[4] = {xv.x, xv.y, xv.z, xv.w};
#pragma unroll
            for (int j = 0; j < 4; ++j) {
                const float* wr = gW + (size_t)(i + j) * N_EXP;
                const float4 w0 = *(const float4*)wr;
                const float4 w1 = *(const float4*)(wr + 4);
                acc[0] += xs[j] * w0.x; acc[1] += xs[j] * w0.y;
                acc[2] += xs[j] * w0.z; acc[3] += xs[j] * w0.w;
                acc[4] += xs[j] * w1.x; acc[5] += xs[j] * w1.y;
                acc[6] += xs[j] * w1.z; acc[7] += xs[j] * w1.w;
            }
        }
#pragma unroll
        for (int off = 32; off > 0; off >>= 1) {
#pragma unroll
            for (int e = 0; e < 8; ++e) acc[e] += __shfl_down(acc[e], off);
        }
        if (lane == 0) {
            float lg[8], mx = -1e30f;
#pragma unroll
            for (int e = 0; e < 8; ++e) {
                lg[e] = acc[e] + gbias[e];
                mx = fmaxf(mx, lg[e]);
            }
            float s = 0.f;
#pragma unroll
            for (int e = 0; e < 8; ++e) { lg[e] = expf(lg[e] - mx); s += lg[e]; }
            const float inv = 1.f / s;
#pragma unroll
            for (int e = 0; e < 8; ++e)
                g_t[(size_t)e * N_TOK + n] = lg[e] * inv;
        }
    } else {
        // zero 32 KB of out
        float4* dst = (float4*)(outz + (size_t)(b - 4096) * 8192);
        const float4 z4 = {0.f, 0.f, 0.f, 0.f};
#pragma unroll
        for (int j = 0; j < 8; ++j) dst[t + 256 * j] = z4;
    }
}

// ---------------------------------------------------------------------------
// GEMM, split-K over experts: grid (8, 64, 2); z -> experts 4z..4z+3.
// 128x128 tile, BK=32, 16 MFMA/wave/barrier (R1-proven inner loop).
// Single accumulator + telescoping gate rescale within the half.
// Partial (incl. this half's bias term) combined via fp32 atomicAdd.
// ---------------------------------------------------------------------------
__global__ __launch_bounds__(256, 4) void moe_gemm3_kernel(
    const unsigned short* __restrict__ xb,   // [N_TOK][D_IN] bf16
    const unsigned short* __restrict__ Wt,   // [D_OUT][KTOT] bf16
    const float* __restrict__ bias,          // [N_EXP][D_OUT]
    const float* __restrict__ g_t,           // [N_EXP][N_TOK]
    float* __restrict__ out) {               // [N_TOK][D_OUT], pre-zeroed
    __shared__ __align__(16) unsigned short Abuf[128 * 32];  // 8 KB
    __shared__ __align__(16) unsigned short Bbuf[128 * 32];  // 8 KB
    __shared__ __align__(16) float g_s[HEXP][128];
    __shared__ __align__(16) float r_s[HEXP][128];  // [e>=1]=d[e-1]/d[e]; [0]=d[3]
    __shared__ __align__(16) float b_s[HEXP][128];

    const int t    = threadIdx.x;
    const int lane = t & 63;
    const int ln15 = lane & 15;
    const int quad = lane >> 4;
    const int wave = t >> 6;
    const int wm0  = (wave >> 1) * 64;
    const int wn0  = (wave & 1) * 64;
    const int bm0  = blockIdx.y * 128;
    const int bn0  = blockIdx.x * 128;
    const int E0   = blockIdx.z * HEXP;

    for (int j = t; j < HEXP * 128; j += 256) {
        const int e = j >> 7, r = j & 127;
        g_s[e][r] = g_t[(size_t)(E0 + e) * N_TOK + bm0 + r];
        b_s[e][r] = bias[(size_t)(E0 + e) * D_OUT + bn0 + r];
    }
    __syncthreads();
    if (t < 128) {
        float d[HEXP];
#pragma unroll
        for (int e = 0; e < HEXP; ++e) d[e] = fmaxf(g_s[e][t], 1e-30f);
#pragma unroll
        for (int e = 1; e < HEXP; ++e) r_s[e][t] = d[e - 1] / d[e];
        r_s[0][t] = d[HEXP - 1];
    }

    f32x4 acc[4][4];
#pragma unroll
    for (int mi = 0; mi < 4; ++mi)
#pragma unroll
        for (int ni = 0; ni < 4; ++ni)
            acc[mi][ni] = (f32x4){0.f, 0.f, 0.f, 0.f};

    unsigned short* aLds0 = &Abuf[wave * 512];
    unsigned short* aLds1 = &Abuf[2048 + wave * 512];
    unsigned short* bLds0 = &Bbuf[wave * 512];
    unsigned short* bLds1 = &Bbuf[2048 + wave * 512];

    const unsigned short* ga =
        xb + (size_t)(bm0 + (t >> 2)) * D_IN + (t & 3) * 8;
    const unsigned short* gbB =
        Wt + (size_t)(bn0 + (t >> 2)) * KTOT + (t & 3) * 8;

    __syncthreads();  // r_s ready

    for (int e = 0; e < HEXP; ++e) {
        if (e) {
#pragma unroll
            for (int mi = 0; mi < 4; ++mi) {
                const f32x4 rv = *(const f32x4*)&r_s[e][wm0 + mi * 16 + quad * 4];
#pragma unroll
                for (int ni = 0; ni < 4; ++ni)
#pragma unroll
                    for (int r = 0; r < 4; ++r) acc[mi][ni][r] *= rv[r];
            }
        }
        const unsigned short* gbe = gbB + (size_t)(E0 + e) * D_IN;

        for (int kk = 0; kk < 32; ++kk) {
            __syncthreads();
            load_lds16(ga + kk * 32,              aLds0);
            load_lds16(ga + 64 * D_IN + kk * 32,  aLds1);
            load_lds16(gbe + kk * 32,             bLds0);
            load_lds16(gbe + 64 * KTOT + kk * 32, bLds1);
            __syncthreads();

            short8 af[4], bv[4];
#pragma unroll
            for (int mi = 0; mi < 4; ++mi)
                af[mi] = *(const short8*)&Abuf[(wm0 + mi * 16 + ln15) * 32 + quad * 8];
#pragma unroll
            for (int ni = 0; ni < 4; ++ni)
                bv[ni] = *(const short8*)&Bbuf[(wn0 + ni * 16 + ln15) * 32 + quad * 8];
#pragma unroll
            for (int mi = 0; mi < 4; ++mi)
#pragma unroll
                for (int ni = 0; ni < 4; ++ni)
                    acc[mi][ni] = __builtin_amdgcn_mfma_f32_16x16x32_bf16(
                        af[mi], bv[ni], acc[mi][ni], 0, 0, 0);
        }
    }

    // final scale by d[last], add this half's bias term, atomic combine
#pragma unroll
    for (int mi = 0; mi < 4; ++mi) {
        const f32x4 fin = *(const f32x4*)&r_s[0][wm0 + mi * 16 + quad * 4];
#pragma unroll
        for (int ni = 0; ni < 4; ++ni)
#pragma unroll
            for (int r = 0; r < 4; ++r) acc[mi][ni][r] *= fin[r];
    }
#pragma unroll
    for (int e = 0; e < HEXP; ++e) {
        f32x4 gv[4];
        float bv[4];
#pragma unroll
        for (int mi = 0; mi < 4; ++mi)
            gv[mi] = *(const f32x4*)&g_s[e][wm0 + mi * 16 + quad * 4];
#pragma unroll
        for (int ni = 0; ni < 4; ++ni) bv[ni] = b_s[e][wn0 + ni * 16 + ln15];
#pragma unroll
        for (int mi = 0; mi < 4; ++mi)
#pragma unroll
            for (int ni = 0; ni < 4; ++ni)
#pragma unroll
                for (int r = 0; r < 4; ++r)
                    acc[mi][ni][r] += gv[mi][r] * bv[ni];
    }

#pragma unroll
    for (int mi = 0; mi < 4; ++mi) {
#pragma unroll
        for (int ni = 0; ni < 4; ++ni) {
            const int col  = bn0 + wn0 + ni * 16 + ln15;
            const int row0 = bm0 + wm0 + mi * 16 + quad * 4;
#pragma unroll
            for (int r = 0; r < 4; ++r)
                atomicAdd(&out[(size_t)(row0 + r) * D_OUT + col],
                          acc[mi][ni][r]);
        }
    }
}

// ---------------------------------------------------------------------------
extern "C" void kernel_launch(void* const* d_in, const int* in_sizes, int n_in,
                              void* d_out, int out_size, void* d_ws, size_t ws_size,
                              hipStream_t stream) {
    const float* x  = (const float*)d_in[0];
    const float* W  = (const float*)d_in[1];
    const float* b  = (const float*)d_in[2];
    const float* gW = (const float*)d_in[3];
    const float* gb = (const float*)d_in[4];
    float* out = (float*)d_out;

    unsigned short* xb  = (unsigned short*)d_ws;                 // 16 MB
    unsigned short* Wt  = xb + (size_t)N_TOK * D_IN;             // 16 MB
    float*          g_t = (float*)(Wt + (size_t)D_OUT * KTOT);   // 256 KB

    prep_kernel<<<5120, 256, 0, stream>>>(x, gW, gb, W, xb, Wt, g_t, out);
    moe_gemm3_kernel<<<dim3(D_OUT / 128, N_TOK / 128, 2), 256, 0, stream>>>(
        xb, Wt, b, g_t, out);
}

// Round 5
// 282.632 us; speedup vs baseline: 1.4664x; 1.1519x over previous
//
#include <hip/hip_runtime.h>
#include <hip/hip_bf16.h>
#include <cstdint>
#include <cstddef>

#define N_TOK 8192
#define D_IN  1024
#define D_OUT 1024
#define N_EXP 8
#define KTOT  (N_EXP * D_IN)

typedef __attribute__((ext_vector_type(8))) short short8;
typedef __attribute__((ext_vector_type(8))) unsigned short ushort8;
typedef __attribute__((ext_vector_type(4))) float f32x4;

__device__ __forceinline__ unsigned short f2bf(float f) {
    union { float f; unsigned int u; } v; v.f = f;
    return (unsigned short)((v.u + 0x7FFFu + ((v.u >> 16) & 1u)) >> 16);
}

__device__ __forceinline__ void load_lds16(const void* g, void* l) {
    __builtin_amdgcn_global_load_lds(
        (const __attribute__((address_space(1))) void*)g,
        (__attribute__((address_space(3))) void*)l,
        16, 0, 0);
}

// ---------------------------------------------------------------------------
// Fused prep, 4096 blocks:
//   [0,2048)    : W[e][i][o] fp32 -> Wt[o][e*1024+i] bf16 (64x64 transpose)
//   [2048,4096) : gate softmax + x->bf16, one wave per token (4 tok/block)
// ---------------------------------------------------------------------------
__global__ __launch_bounds__(256) void prep_kernel(
    const float* __restrict__ x, const float* __restrict__ gW,
    const float* __restrict__ gbias, const float* __restrict__ W,
    unsigned short* __restrict__ xb, unsigned short* __restrict__ Wt,
    float* __restrict__ g_t) {
    const int b = blockIdx.x;
    const int t = threadIdx.x;

    if (b < 2048) {
        __shared__ float tile[64][65];
        const int e  = b >> 8;
        const int i0 = ((b >> 4) & 15) * 64;
        const int o0 = (b & 15) * 64;

        const int rr = t >> 4;
        const int rc = (t & 15) * 4;
#pragma unroll
        for (int j = 0; j < 4; ++j) {
            const float4 v = *(const float4*)(
                W + ((size_t)e * D_IN + (i0 + rr + 16 * j)) * D_OUT + o0 + rc);
            tile[rr + 16 * j][rc + 0] = v.x;
            tile[rr + 16 * j][rc + 1] = v.y;
            tile[rr + 16 * j][rc + 2] = v.z;
            tile[rr + 16 * j][rc + 3] = v.w;
        }
        __syncthreads();
        const int ow = t >> 2;
        const int c  = (t & 3) * 16;
        ushort8 v0, v1;
#pragma unroll
        for (int j = 0; j < 8; ++j) v0[j] = f2bf(tile[c + j][ow]);
#pragma unroll
        for (int j = 0; j < 8; ++j) v1[j] = f2bf(tile[c + 8 + j][ow]);
        unsigned short* dst = Wt + (size_t)(o0 + ow) * KTOT + e * D_IN + i0 + c;
        *(ushort8*)dst = v0;
        *(ushort8*)(dst + 8) = v1;
    } else {
        const int lane = t & 63;
        const int n    = (b - 2048) * 4 + (t >> 6);

        float acc[8];
#pragma unroll
        for (int e = 0; e < 8; ++e) acc[e] = 0.f;
#pragma unroll
        for (int jj = 0; jj < 4; ++jj) {
            const int i = 256 * jj + 4 * lane;
            const float4 xv = *(const float4*)(x + (size_t)n * D_IN + i);
            ushort4 u;
            u.x = f2bf(xv.x); u.y = f2bf(xv.y);
            u.z = f2bf(xv.z); u.w = f2bf(xv.w);
            *(ushort4*)(xb + (size_t)n * D_IN + i) = u;
            const float xs[4] = {xv.x, xv.y, xv.z, xv.w};
#pragma unroll
            for (int j = 0; j < 4; ++j) {
                const float* wr = gW + (size_t)(i + j) * N_EXP;
                const float4 w0 = *(const float4*)wr;
                const float4 w1 = *(const float4*)(wr + 4);
                acc[0] += xs[j] * w0.x; acc[1] += xs[j] * w0.y;
                acc[2] += xs[j] * w0.z; acc[3] += xs[j] * w0.w;
                acc[4] += xs[j] * w1.x; acc[5] += xs[j] * w1.y;
                acc[6] += xs[j] * w1.z; acc[7] += xs[j] * w1.w;
            }
        }
#pragma unroll
        for (int off = 32; off > 0; off >>= 1) {
#pragma unroll
            for (int e = 0; e < 8; ++e) acc[e] += __shfl_down(acc[e], off);
        }
        if (lane == 0) {
            float lg[8], mx = -1e30f;
#pragma unroll
            for (int e = 0; e < 8; ++e) {
                lg[e] = acc[e] + gbias[e];
                mx = fmaxf(mx, lg[e]);
            }
            float s = 0.f;
#pragma unroll
            for (int e = 0; e < 8; ++e) { lg[e] = expf(lg[e] - mx); s += lg[e]; }
            const float inv = 1.f / s;
#pragma unroll
            for (int e = 0; e < 8; ++e)
                g_t[(size_t)e * N_TOK + n] = lg[e] * inv;
        }
    }
}

// ---------------------------------------------------------------------------
// GEMM: 128x128 tile, K unrolled x2 (two BK=32 LDS tile-sets per barrier
// pair -> 32 MFMA/wave per drain instead of 16). Single accumulator +
// telescoping gate rescale; bias via epilogue rank-8 update; plain stores.
// Grid (8,64) = 512 blocks = 2 blocks/CU (grid-pinned).
// ---------------------------------------------------------------------------
__global__ __launch_bounds__(256, 2) void moe_gemm4_kernel(
    const unsigned short* __restrict__ xb,   // [N_TOK][D_IN] bf16
    const unsigned short* __restrict__ Wt,   // [D_OUT][KTOT] bf16
    const float* __restrict__ bias,          // [N_EXP][D_OUT]
    const float* __restrict__ g_t,           // [N_EXP][N_TOK]
    float* __restrict__ out) {               // [N_TOK][D_OUT]
    __shared__ __align__(16) unsigned short Abuf[2][128 * 32];  // 16 KB
    __shared__ __align__(16) unsigned short Bbuf[2][128 * 32];  // 16 KB
    __shared__ __align__(16) float g_s[N_EXP][128];
    __shared__ __align__(16) float r_s[N_EXP][128];  // [e>=1]=d[e-1]/d[e]; [0]=d[7]
    __shared__ __align__(16) float b_s[N_EXP][128];

    const int t    = threadIdx.x;
    const int lane = t & 63;
    const int ln15 = lane & 15;
    const int quad = lane >> 4;
    const int wave = t >> 6;
    const int wm0  = (wave >> 1) * 64;
    const int wn0  = (wave & 1) * 64;
    const int bm0  = blockIdx.y * 128;
    const int bn0  = blockIdx.x * 128;

    for (int j = t; j < N_EXP * 128; j += 256) {
        const int e = j >> 7, r = j & 127;
        g_s[e][r] = g_t[(size_t)e * N_TOK + bm0 + r];
        b_s[e][r] = bias[(size_t)e * D_OUT + bn0 + r];
    }
    __syncthreads();
    if (t < 128) {
        float d[N_EXP];
#pragma unroll
        for (int e = 0; e < N_EXP; ++e) d[e] = fmaxf(g_s[e][t], 1e-30f);
#pragma unroll
        for (int e = 1; e < N_EXP; ++e) r_s[e][t] = d[e - 1] / d[e];
        r_s[0][t] = d[N_EXP - 1];
    }

    f32x4 acc[4][4];
#pragma unroll
    for (int mi = 0; mi < 4; ++mi)
#pragma unroll
        for (int ni = 0; ni < 4; ++ni)
            acc[mi][ni] = (f32x4){0.f, 0.f, 0.f, 0.f};

    // wave-uniform staging bases for each of the two tile-sets
    unsigned short* aL0[2] = {&Abuf[0][wave * 512], &Abuf[1][wave * 512]};
    unsigned short* aL1[2] = {&Abuf[0][2048 + wave * 512], &Abuf[1][2048 + wave * 512]};
    unsigned short* bL0[2] = {&Bbuf[0][wave * 512], &Bbuf[1][wave * 512]};
    unsigned short* bL1[2] = {&Bbuf[0][2048 + wave * 512], &Bbuf[1][2048 + wave * 512]};

    const unsigned short* ga =
        xb + (size_t)(bm0 + (t >> 2)) * D_IN + (t & 3) * 8;
    const unsigned short* gbB =
        Wt + (size_t)(bn0 + (t >> 2)) * KTOT + (t & 3) * 8;

    __syncthreads();  // r_s ready

    for (int e = 0; e < N_EXP; ++e) {
        if (e) {  // telescope: acc *= d[e-1]/d[e]
#pragma unroll
            for (int mi = 0; mi < 4; ++mi) {
                const f32x4 rv = *(const f32x4*)&r_s[e][wm0 + mi * 16 + quad * 4];
#pragma unroll
                for (int ni = 0; ni < 4; ++ni)
#pragma unroll
                    for (int r = 0; r < 4; ++r) acc[mi][ni][r] *= rv[r];
            }
        }
        const unsigned short* gbe = gbB + (size_t)e * D_IN;

        for (int kk = 0; kk < 32; kk += 2) {
            __syncthreads();
            // stage BOTH k-slices under one barrier pair
            load_lds16(ga + kk * 32,                    aL0[0]);
            load_lds16(ga + 64 * D_IN + kk * 32,        aL1[0]);
            load_lds16(gbe + kk * 32,                   bL0[0]);
            load_lds16(gbe + 64 * KTOT + kk * 32,       bL1[0]);
            load_lds16(ga + (kk + 1) * 32,              aL0[1]);
            load_lds16(ga + 64 * D_IN + (kk + 1) * 32,  aL1[1]);
            load_lds16(gbe + (kk + 1) * 32,             bL0[1]);
            load_lds16(gbe + 64 * KTOT + (kk + 1) * 32, bL1[1]);
            __syncthreads();

#pragma unroll
            for (int s = 0; s < 2; ++s) {
                short8 af[4], bv[4];
#pragma unroll
                for (int mi = 0; mi < 4; ++mi)
                    af[mi] = *(const short8*)
                        &Abuf[s][(wm0 + mi * 16 + ln15) * 32 + quad * 8];
#pragma unroll
                for (int ni = 0; ni < 4; ++ni)
                    bv[ni] = *(const short8*)
                        &Bbuf[s][(wn0 + ni * 16 + ln15) * 32 + quad * 8];
#pragma unroll
                for (int mi = 0; mi < 4; ++mi)
#pragma unroll
                    for (int ni = 0; ni < 4; ++ni)
                        acc[mi][ni] = __builtin_amdgcn_mfma_f32_16x16x32_bf16(
                            af[mi], bv[ni], acc[mi][ni], 0, 0, 0);
            }
        }
    }

    // final telescope scale by d[7], then add sum_e g_e * b[e][col]
#pragma unroll
    for (int mi = 0; mi < 4; ++mi) {
        const f32x4 fin = *(const f32x4*)&r_s[0][wm0 + mi * 16 + quad * 4];
#pragma unroll
        for (int ni = 0; ni < 4; ++ni)
#pragma unroll
            for (int r = 0; r < 4; ++r) acc[mi][ni][r] *= fin[r];
    }
#pragma unroll
    for (int e = 0; e < N_EXP; ++e) {
        f32x4 gv[4];
        float bv[4];
#pragma unroll
        for (int mi = 0; mi < 4; ++mi)
            gv[mi] = *(const f32x4*)&g_s[e][wm0 + mi * 16 + quad * 4];
#pragma unroll
        for (int ni = 0; ni < 4; ++ni) bv[ni] = b_s[e][wn0 + ni * 16 + ln15];
#pragma unroll
        for (int mi = 0; mi < 4; ++mi)
#pragma unroll
            for (int ni = 0; ni < 4; ++ni)
#pragma unroll
                for (int r = 0; r < 4; ++r)
                    acc[mi][ni][r] += gv[mi][r] * bv[ni];
    }

#pragma unroll
    for (int mi = 0; mi < 4; ++mi) {
#pragma unroll
        for (int ni = 0; ni < 4; ++ni) {
            const int col  = bn0 + wn0 + ni * 16 + ln15;
            const int row0 = bm0 + wm0 + mi * 16 + quad * 4;
#pragma unroll
            for (int r = 0; r < 4; ++r)
                out[(size_t)(row0 + r) * D_OUT + col] = acc[mi][ni][r];
        }
    }
}

// ---------------------------------------------------------------------------
extern "C" void kernel_launch(void* const* d_in, const int* in_sizes, int n_in,
                              void* d_out, int out_size, void* d_ws, size_t ws_size,
                              hipStream_t stream) {
    const float* x  = (const float*)d_in[0];
    const float* W  = (const float*)d_in[1];
    const float* b  = (const float*)d_in[2];
    const float* gW = (const float*)d_in[3];
    const float* gb = (const float*)d_in[4];
    float* out = (float*)d_out;

    unsigned short* xb  = (unsigned short*)d_ws;                 // 16 MB
    unsigned short* Wt  = xb + (size_t)N_TOK * D_IN;             // 16 MB
    float*          g_t = (float*)(Wt + (size_t)D_OUT * KTOT);   // 256 KB

    prep_kernel<<<4096, 256, 0, stream>>>(x, gW, gb, W, xb, Wt, g_t);
    moe_gemm4_kernel<<<dim3(D_OUT / 128, N_TOK / 128), 256, 0, stream>>>(
        xb, Wt, b, g_t, out);
}